// Round 1
// baseline (242.345 us; speedup 1.0000x reference)
//
#include <hip/hip_runtime.h>

typedef __attribute__((ext_vector_type(8))) short bf16x8;
typedef __attribute__((ext_vector_type(4))) float f32x4;
typedef __attribute__((ext_vector_type(8))) unsigned short u16x8;
typedef unsigned int u32;
typedef unsigned short u16;

#define CIN 512
#define CO  512
#define HH  64
#define WW  64
#define BB  8
#define HP  66
#define WPAD 68
#define KK  4608  // CIN*9

#define SIG_BYTES  (BB*CO*4)                       // 16384
#define WMOD_ELEMS ((size_t)BB*9*64*CO*8)          // 18,874,368
#define WMOD_BYTES (WMOD_ELEMS*2)                  // 37,748,736
#define IMGT_ELEMS ((size_t)BB*HP*WPAD*CIN)        // 18,382,848
#define IMGT_BYTES (IMGT_ELEMS*2)                  // 36,765,696
#define WS_NEED    ((size_t)SIG_BYTES + WMOD_BYTES + IMGT_BYTES)

__device__ __forceinline__ u16 f2bf(float f) {
  union { float f; u32 u; } v; v.f = f;
  u32 r = (v.u + 0x7FFFu + ((v.u >> 16) & 1u)) >> 16;  // RNE
  return (u16)r;
}

// ---------------- K1: sigma[b][o] = rsqrt(sum_i,t (w*(s+1))^2 + eps) ----------
__global__ void k_sigma(const float* __restrict__ weight, const float* __restrict__ s,
                        float* __restrict__ sigma) {
  int o = blockIdx.x;          // 512 blocks
  int tid = threadIdx.x;       // 256 threads
  const float* wrow = weight + (size_t)o * KK;
  float acc[BB];
#pragma unroll
  for (int b = 0; b < BB; ++b) acc[b] = 0.f;
  for (int e = tid; e < KK; e += 256) {
    float w = wrow[e];
    float w2 = w * w;
    int i = e / 9;
#pragma unroll
    for (int b = 0; b < BB; ++b) {
      float m = s[b * CIN + i] + 1.0f;
      acc[b] += w2 * m * m;
    }
  }
#pragma unroll
  for (int b = 0; b < BB; ++b) {
#pragma unroll
    for (int off = 32; off >= 1; off >>= 1)
      acc[b] += __shfl_down(acc[b], off);
  }
  __shared__ float red[4][BB];
  int wv = tid >> 6, ln = tid & 63;
  if (ln == 0) {
#pragma unroll
    for (int b = 0; b < BB; ++b) red[wv][b] = acc[b];
  }
  __syncthreads();
  if (tid < BB) {
    float t = red[0][tid] + red[1][tid] + red[2][tid] + red[3][tid];
    sigma[tid * CO + o] = rsqrtf(t + 1e-8f);
  }
}

// ------------- K2: wmod[b][t][kg][o][8] bf16 = W*(s+1)*sigma (A-frag layout) --
__global__ void k_wmod(const float* __restrict__ weight, const float* __restrict__ s,
                       const float* __restrict__ sigma, u16* __restrict__ wmod) {
  int gid = blockIdx.x * 256 + threadIdx.x;   // 8*9*64*512 threads
  int o  = gid & 511;
  int r1 = gid >> 9;
  int kg = r1 & 63;
  int bt = r1 >> 6;            // b*9 + t, 0..71
  int b = bt / 9;
  int t = bt - b * 9;
  float sig = sigma[b * CO + o];
  const float* wbase = weight + (size_t)o * KK + t;  // element (o,i,t) = (o*512+i)*9+t
  u16x8 ov;
#pragma unroll
  for (int j = 0; j < 8; ++j) {
    int i = kg * 8 + j;
    float w = wbase[(size_t)i * 9];
    float m = s[b * CIN + i] + 1.0f;
    ov[j] = f2bf(w * m * sig);
  }
  *(u16x8*)(wmod + ((size_t)(bt * 64 + kg) * CO + o) * 8) = ov;
}

// ------------- K3: imgt[b][yp(66)][xp(68)][i] bf16, zero-padded ---------------
__global__ void k_imgt(const float* __restrict__ img, u16* __restrict__ imgt) {
  int bid = blockIdx.x;        // 8*64*2*8 = 8192 blocks
  int ic = bid & 7;  int r = bid >> 3;
  int xc = r & 1;    r >>= 1;
  int y  = r & 63;   int b = r >> 6;
  int tid = threadIdx.x;
  __shared__ float lt[64][33];
  {
    int ii = tid >> 2, xq = tid & 3;   // ii: 64 channels, xq: 4 groups of 8 x
    const float* src = img + (((size_t)(b * CIN + ic * 64 + ii)) * HH + y) * WW + xc * 32 + xq * 8;
    float4 v0 = *(const float4*)src;
    float4 v1 = *(const float4*)(src + 4);
    int xb = xq * 8;
    lt[ii][xb+0]=v0.x; lt[ii][xb+1]=v0.y; lt[ii][xb+2]=v0.z; lt[ii][xb+3]=v0.w;
    lt[ii][xb+4]=v1.x; lt[ii][xb+5]=v1.y; lt[ii][xb+6]=v1.z; lt[ii][xb+7]=v1.w;
  }
  __syncthreads();
  int xl = tid >> 3, iq = tid & 7;
  u16x8 ov;
#pragma unroll
  for (int j = 0; j < 8; ++j) ov[j] = f2bf(lt[iq*8+j][xl]);
  size_t dst = (((size_t)b * HP + (y + 1)) * WPAD + (xc * 32 + xl + 1)) * CIN + ic * 64 + iq * 8;
  *(u16x8*)(imgt + dst) = ov;
}

// ---------------- K4: implicit-GEMM conv, BM=128 x BN=128(2x64) x BK=32 -------
__device__ __forceinline__ void async16(const u16* g, void* lds) {
  __builtin_amdgcn_global_load_lds((const __attribute__((address_space(1))) u32*)g,
                                   (__attribute__((address_space(3))) u32*)lds, 16, 0, 0);
}

__global__ __launch_bounds__(256) void k_conv(const u16* __restrict__ wmod,
                                              const u16* __restrict__ imgt,
                                              float* __restrict__ out) {
  __shared__ alignas(16) char tile[17408];   // 272 positions x 64B (swizzled)
  int bid = blockIdx.x;                      // 1024 = 8b * 4ot * 32pt
  int b   = bid >> 7;
  int rem = bid & 127;
  int ot  = rem >> 5;
  int pt  = rem & 31;
  int y0    = pt * 2;
  int obase = ot * 128;
  int tid = threadIdx.x;
  int wave = tid >> 6, lane = tid & 63;
  int wm = wave >> 1, wn = wave & 1;
  int col0 = lane & 15, kg = lane >> 4;

  // Staging source offsets. LDS is written linearly (base + lane*16); reads use
  // phys = L ^ ((P&7)<<4). So the source for physical addr A is logical
  // L = inv_swz(A): L4=A4^A6^A8, L5=A5^A7, L6=A6^A8 (bijective, verified).
  int srcoff[5];
#pragma unroll
  for (int jj = 0; jj < 5; ++jj) {
    int j = wave + jj * 4;
    if (j < 17) {
      int A = j * 1024 + lane * 16;
      int L = A ^ ((A >> 2) & 0x70) ^ ((A >> 4) & 0x10);
      int P = L >> 6;
      int sl = (L >> 4) & 3;
      int rr = P / 68;
      int cc = P - rr * 68;
      srcoff[jj] = ((b * HP + (y0 + rr)) * WPAD + cc) * CIN + sl * 8;
    } else srcoff[jj] = 0;
  }

  f32x4 zero = {0.f, 0.f, 0.f, 0.f};
  f32x4 acc[4][4];
#pragma unroll
  for (int i = 0; i < 4; ++i)
#pragma unroll
    for (int j = 0; j < 4; ++j) acc[i][j] = zero;

  const bf16x8* wv = (const bf16x8*)wmod;

  for (int icc = 0; icc < 16; ++icc) {
    __syncthreads();
#pragma unroll
    for (int jj = 0; jj < 5; ++jj) {
      int j = wave + jj * 4;
      if (j < 17)
        async16(imgt + srcoff[jj] + icc * 32, (void*)(tile + j * 1024));
    }
    __syncthreads();   // compiler drains vmcnt before barrier
#pragma unroll
    for (int t = 0; t < 9; ++t) {
      int ky = t / 3, kx = t - ky * 3;
      bf16x8 af[4];
#pragma unroll
      for (int am = 0; am < 4; ++am) {
        int idx = ((b * 9 + t) * 64 + icc * 4 + kg) * CO + (obase + wm * 64 + am * 16 + col0);
        af[am] = wv[idx];
      }
#pragma unroll
      for (int an = 0; an < 4; ++an) {
        int P = (wn + ky) * WPAD + an * 16 + col0 + kx;
        int L = P * 64 + kg * 16;
        int phys = L ^ ((P & 7) << 4);
        bf16x8 bv = *(const bf16x8*)(tile + phys);
#pragma unroll
        for (int am = 0; am < 4; ++am)
          acc[am][an] = __builtin_amdgcn_mfma_f32_16x16x32_bf16(af[am], bv, acc[am][an], 0, 0, 0);
      }
    }
  }

  int y = y0 + wn;
#pragma unroll
  for (int am = 0; am < 4; ++am) {
    int o = obase + wm * 64 + am * 16 + kg * 4;   // row = (lane>>4)*4 + reg
#pragma unroll
    for (int an = 0; an < 4; ++an) {
      int x = an * 16 + col0;                      // col = lane&15
      float* op = out + (((size_t)(b * CO + o)) * HH + y) * WW + x;
#pragma unroll
      for (int rg = 0; rg < 4; ++rg)
        op[(size_t)rg * HH * WW] = acc[am][an][rg];
    }
  }
}

// ---------------- Fallback (ws too small): naive but correct ------------------
__global__ void k_naive(const float* __restrict__ img, const float* __restrict__ s,
                        const float* __restrict__ weight, const float* __restrict__ sigma,
                        float* __restrict__ out) {
  int bid = blockIdx.x;          // 8*512*64, 64 threads
  int y = bid & 63; int r = bid >> 6; int o = r & 511; int b = r >> 9;
  int x = threadIdx.x;
  float sig = sigma[b * CO + o];
  float acc = 0.f;
  for (int i = 0; i < CIN; ++i) {
    float m = s[b * CIN + i] + 1.0f;
    const float* wp = weight + ((size_t)o * CIN + i) * 9;
    const float* ip = img + ((size_t)(b * CIN + i)) * HH * WW;
#pragma unroll
    for (int ky = 0; ky < 3; ++ky) {
      int yy = y + ky - 1;
      if (yy < 0 || yy > 63) continue;
#pragma unroll
      for (int kx = 0; kx < 3; ++kx) {
        int xx = x + kx - 1;
        float iv = (xx >= 0 && xx < 64) ? ip[yy * 64 + xx] : 0.f;
        acc += wp[ky * 3 + kx] * m * iv;
      }
    }
  }
  out[((size_t)(b * CO + o) * HH + y) * WW + x] = acc * sig;
}

extern "C" void kernel_launch(void* const* d_in, const int* in_sizes, int n_in,
                              void* d_out, int out_size, void* d_ws, size_t ws_size,
                              hipStream_t stream) {
  const float* img    = (const float*)d_in[0];
  const float* s      = (const float*)d_in[1];
  const float* weight = (const float*)d_in[2];
  float* out = (float*)d_out;
  char* ws = (char*)d_ws;
  float* sigma = (float*)ws;

  if (ws_size >= WS_NEED) {
    u16* wmod = (u16*)(ws + SIG_BYTES);
    u16* imgt = (u16*)(ws + SIG_BYTES + WMOD_BYTES);
    k_sigma<<<512, 256, 0, stream>>>(weight, s, sigma);
    k_wmod<<<(int)(WMOD_ELEMS / 8 / 256), 256, 0, stream>>>(weight, s, sigma, wmod);
    hipMemsetAsync(imgt, 0, IMGT_BYTES, stream);
    k_imgt<<<8192, 256, 0, stream>>>(img, imgt);
    k_conv<<<1024, 256, 0, stream>>>(wmod, imgt, out);
  } else {
    k_sigma<<<512, 256, 0, stream>>>(weight, s, sigma);
    k_naive<<<BB * CO * HH, 64, 0, stream>>>(img, s, weight, sigma, out);
  }
}

// Round 2
// 214.545 us; speedup vs baseline: 1.1296x; 1.1296x over previous
//
#include <hip/hip_runtime.h>

typedef __attribute__((ext_vector_type(8))) short bf16x8;
typedef __attribute__((ext_vector_type(4))) float f32x4;
typedef __attribute__((ext_vector_type(8))) unsigned short u16x8;
typedef unsigned int u32;
typedef unsigned short u16;

#define CIN 512
#define CO  512
#define HH  64
#define WW  64
#define BB  8
#define HP  66
#define WPAD 68
#define KK  4608  // CIN*9

#define SIG_BYTES  (BB*CO*4)                       // 16384
#define WMOD_ELEMS ((size_t)BB*9*64*CO*8)          // 18,874,368
#define WMOD_BYTES (WMOD_ELEMS*2)                  // 37,748,736
#define IMGT_ELEMS ((size_t)BB*HP*WPAD*CIN)        // 18,382,848
#define IMGT_BYTES (IMGT_ELEMS*2)                  // 36,765,696
#define WS_NEED    ((size_t)SIG_BYTES + WMOD_BYTES + IMGT_BYTES)

__device__ __forceinline__ u16 f2bf(float f) {
  union { float f; u32 u; } v; v.f = f;
  u32 r = (v.u + 0x7FFFu + ((v.u >> 16) & 1u)) >> 16;  // RNE
  return (u16)r;
}

// ---------------- K1: sigma[b][o] = rsqrt(sum_i,t (w*(s+1))^2 + eps) ----------
__global__ void k_sigma(const float* __restrict__ weight, const float* __restrict__ s,
                        float* __restrict__ sigma) {
  int o = blockIdx.x;          // 512 blocks
  int tid = threadIdx.x;       // 256 threads
  const float* wrow = weight + (size_t)o * KK;
  float acc[BB];
#pragma unroll
  for (int b = 0; b < BB; ++b) acc[b] = 0.f;
  for (int e = tid; e < KK; e += 256) {
    float w = wrow[e];
    float w2 = w * w;
    int i = e / 9;
#pragma unroll
    for (int b = 0; b < BB; ++b) {
      float m = s[b * CIN + i] + 1.0f;
      acc[b] += w2 * m * m;
    }
  }
#pragma unroll
  for (int b = 0; b < BB; ++b) {
#pragma unroll
    for (int off = 32; off >= 1; off >>= 1)
      acc[b] += __shfl_down(acc[b], off);
  }
  __shared__ float red[4][BB];
  int wv = tid >> 6, ln = tid & 63;
  if (ln == 0) {
#pragma unroll
    for (int b = 0; b < BB; ++b) red[wv][b] = acc[b];
  }
  __syncthreads();
  if (tid < BB) {
    float t = red[0][tid] + red[1][tid] + red[2][tid] + red[3][tid];
    sigma[tid * CO + o] = rsqrtf(t + 1e-8f);
  }
}

// ------------- K2: wmod[b][t][kg][o][8] bf16, LDS-staged coalesced ------------
__global__ __launch_bounds__(256) void k_wmod(const float* __restrict__ weight,
                                              const float* __restrict__ s,
                                              const float* __restrict__ sigma,
                                              u16* __restrict__ wmod) {
  __shared__ float lw[16][577];
  int bid = blockIdx.x;        // 256 = 32 oc * 8 ic
  int oc = bid & 31, ic = bid >> 5;
  int o0 = oc * 16;
  int tid = threadIdx.x;
  // cooperative coalesced load: weight[o0..o0+16)[ic*576 .. +576) = 2304 float4
  const float* wsrc = weight + (size_t)o0 * KK + ic * 576;
#pragma unroll
  for (int k = 0; k < 9; ++k) {
    int f4 = tid + k * 256;            // 0..2303
    int row = f4 / 144;                // 144 float4 per row
    int col = f4 - row * 144;
    float4 v = *(const float4*)(wsrc + (size_t)row * KK + col * 4);
    lw[row][col*4+0]=v.x; lw[row][col*4+1]=v.y; lw[row][col*4+2]=v.z; lw[row][col*4+3]=v.w;
  }
  __syncthreads();
  int o_l = tid & 15, kg_l = (tid >> 4) & 7;
#pragma unroll
  for (int k = 0; k < 36; ++k) {
    int bt = k * 2 + (tid >> 7);       // 0..71
    int b = bt / 9;
    int t = bt - b * 9;
    int o = o0 + o_l;
    float sig = sigma[b * CO + o];
    u16x8 ov;
#pragma unroll
    for (int j = 0; j < 8; ++j) {
      int il = kg_l * 8 + j;
      float w = lw[o_l][il * 9 + t];
      float m = s[b * CIN + ic * 64 + il] + 1.0f;
      ov[j] = f2bf(w * m * sig);
    }
    *(u16x8*)(wmod + ((size_t)(bt * 64 + (ic * 8 + kg_l)) * CO + o) * 8) = ov;
  }
}

// ------------- K3a: zero the pad border of imgt (replaces 36.8MB memset) ------
__global__ void k_pad(u16* __restrict__ imgt) {
  int gid = blockIdx.x * 256 + threadIdx.x;   // 528*256 = 135168 vec-stores
  int c8 = gid & 63;
  int pos = gid >> 6;                         // 0..2111 = 8b * 264
  int b = pos / 264;
  int pr = pos - b * 264;
  int yp, xp;
  if (pr < 136) { yp = (pr < 68) ? 0 : 65; xp = (pr < 68) ? pr : pr - 68; }
  else { int q = pr - 136; yp = 1 + (q >> 1); xp = (q & 1) ? 67 : 0; }
  u16x8 z = {0,0,0,0,0,0,0,0};
  *(u16x8*)(imgt + (((size_t)b * HP + yp) * WPAD + xp) * CIN + c8 * 8) = z;
}

// ------------- K3b: imgt[b][yp(66)][xp(68)][i] bf16, interior ----------------
__global__ void k_imgt(const float* __restrict__ img, u16* __restrict__ imgt) {
  int bid = blockIdx.x;        // 8*64*2*8 = 8192 blocks
  int ic = bid & 7;  int r = bid >> 3;
  int xc = r & 1;    r >>= 1;
  int y  = r & 63;   int b = r >> 6;
  int tid = threadIdx.x;
  __shared__ float lt[64][33];
  {
    int ii = tid >> 2, xq = tid & 3;
    const float* src = img + (((size_t)(b * CIN + ic * 64 + ii)) * HH + y) * WW + xc * 32 + xq * 8;
    float4 v0 = *(const float4*)src;
    float4 v1 = *(const float4*)(src + 4);
    int xb = xq * 8;
    lt[ii][xb+0]=v0.x; lt[ii][xb+1]=v0.y; lt[ii][xb+2]=v0.z; lt[ii][xb+3]=v0.w;
    lt[ii][xb+4]=v1.x; lt[ii][xb+5]=v1.y; lt[ii][xb+6]=v1.z; lt[ii][xb+7]=v1.w;
  }
  __syncthreads();
  int xl = tid >> 3, iq = tid & 7;
  u16x8 ov;
#pragma unroll
  for (int j = 0; j < 8; ++j) ov[j] = f2bf(lt[iq*8+j][xl]);
  size_t dst = (((size_t)b * HP + (y + 1)) * WPAD + (xc * 32 + xl + 1)) * CIN + ic * 64 + iq * 8;
  *(u16x8*)(imgt + dst) = ov;
}

// ---------------- K4: implicit-GEMM conv, 2-phase dbuf + A-prefetch -----------
__device__ __forceinline__ void async16(const u16* g, void* lds) {
  __builtin_amdgcn_global_load_lds((const __attribute__((address_space(1))) u32*)g,
                                   (__attribute__((address_space(3))) u32*)lds, 16, 0, 0);
}

__global__ __launch_bounds__(256, 3) void k_conv(const u16* __restrict__ wmod,
                                                 const u16* __restrict__ imgt,
                                                 float* __restrict__ out) {
  __shared__ alignas(16) char tile[2][17408];   // dbuf: 272 positions x 64B (swizzled)
  int bid0 = blockIdx.x;                        // 1024
  int bid  = (bid0 & 7) * 128 + (bid0 >> 3);    // XCD-chunked: each XCD owns one b
  int b   = bid >> 7;
  int rem = bid & 127;
  int ot  = rem >> 5;
  int pt  = rem & 31;
  int y0    = pt * 2;
  int obase = ot * 128;
  int tid = threadIdx.x;
  int wave = tid >> 6, lane = tid & 63;
  int wm = wave >> 1, wn = wave & 1;
  int col0 = lane & 15, kg = lane >> 4;

  // Staging source offsets (inverse-swizzled global source, linear LDS dest).
  int srcoff[5];
#pragma unroll
  for (int jj = 0; jj < 5; ++jj) {
    int j = wave + jj * 4;
    if (j < 17) {
      int A = j * 1024 + lane * 16;
      int L = A ^ ((A >> 2) & 0x70) ^ ((A >> 4) & 0x10);
      int P = L >> 6;
      int sl = (L >> 4) & 3;
      int rr = P / 68;
      int cc = P - rr * 68;
      srcoff[jj] = ((b * HP + (y0 + rr)) * WPAD + cc) * CIN + sl * 8;
    } else srcoff[jj] = 0;
  }

#define STAGE(bufi, ic) do { \
  _Pragma("unroll") \
  for (int jj = 0; jj < 5; ++jj) { \
    int j = wave + jj * 4; \
    if (j < 17) async16(imgt + srcoff[jj] + (ic) * 32, (void*)(tile[bufi] + j * 1024)); \
  } } while (0)

  f32x4 zero = {0.f, 0.f, 0.f, 0.f};
  f32x4 acc[4][4];
#pragma unroll
  for (int i = 0; i < 4; ++i)
#pragma unroll
    for (int j = 0; j < 4; ++j) acc[i][j] = zero;

  const bf16x8* wv = (const bf16x8*)wmod;
  int abase = obase + wm * 64 + col0;   // o coordinate of am=0 fragment

  // prologue: stage icc=0, prefetch A(icc=0, t=0)
  STAGE(0, 0);
  bf16x8 af0, af1, af2, af3;
  {
    int idx = ((b * 9 + 0) * 64 + 0 * 4 + kg) * CO + abase;
    af0 = wv[idx]; af1 = wv[idx + 16]; af2 = wv[idx + 32]; af3 = wv[idx + 48];
  }
  __syncthreads();

  for (int icc = 0; icc < 16; ++icc) {
    const char* curb = tile[icc & 1];
    if (icc < 15) STAGE((icc + 1) & 1, icc + 1);
#pragma unroll
    for (int t = 0; t < 9; ++t) {
      bf16x8 a0 = af0, a1 = af1, a2 = af2, a3 = af3;
      // prefetch next tap's A-fragments (crosses into next icc at t==8)
      if (!(t == 8 && icc == 15)) {
        int nt   = (t == 8) ? 0 : t + 1;
        int nicc = (t == 8) ? icc + 1 : icc;
        int idx = ((b * 9 + nt) * 64 + nicc * 4 + kg) * CO + abase;
        af0 = wv[idx]; af1 = wv[idx + 16]; af2 = wv[idx + 32]; af3 = wv[idx + 48];
      }
      int ky = t / 3, kx = t - ky * 3;
#pragma unroll
      for (int an = 0; an < 4; ++an) {
        int P = (wn + ky) * WPAD + an * 16 + col0 + kx;
        int L = P * 64 + kg * 16;
        int phys = L ^ ((P & 7) << 4);
        bf16x8 bv = *(const bf16x8*)(curb + phys);
        acc[0][an] = __builtin_amdgcn_mfma_f32_16x16x32_bf16(a0, bv, acc[0][an], 0, 0, 0);
        acc[1][an] = __builtin_amdgcn_mfma_f32_16x16x32_bf16(a1, bv, acc[1][an], 0, 0, 0);
        acc[2][an] = __builtin_amdgcn_mfma_f32_16x16x32_bf16(a2, bv, acc[2][an], 0, 0, 0);
        acc[3][an] = __builtin_amdgcn_mfma_f32_16x16x32_bf16(a3, bv, acc[3][an], 0, 0, 0);
      }
    }
    __syncthreads();   // drains vmcnt (stage) + lgkmcnt; one barrier per K-step
  }
#undef STAGE

  int y = y0 + wn;
#pragma unroll
  for (int am = 0; am < 4; ++am) {
    int o = obase + wm * 64 + am * 16 + kg * 4;   // row = (lane>>4)*4 + reg
#pragma unroll
    for (int an = 0; an < 4; ++an) {
      int x = an * 16 + col0;                      // col = lane&15
      float* op = out + (((size_t)(b * CO + o)) * HH + y) * WW + x;
#pragma unroll
      for (int rg = 0; rg < 4; ++rg)
        op[(size_t)rg * HH * WW] = acc[am][an][rg];
    }
  }
}

// ---------------- Fallback (ws too small): naive but correct ------------------
__global__ void k_naive(const float* __restrict__ img, const float* __restrict__ s,
                        const float* __restrict__ weight, const float* __restrict__ sigma,
                        float* __restrict__ out) {
  int bid = blockIdx.x;          // 8*512*64, 64 threads
  int y = bid & 63; int r = bid >> 6; int o = r & 511; int b = r >> 9;
  int x = threadIdx.x;
  float sig = sigma[b * CO + o];
  float acc = 0.f;
  for (int i = 0; i < CIN; ++i) {
    float m = s[b * CIN + i] + 1.0f;
    const float* wp = weight + ((size_t)o * CIN + i) * 9;
    const float* ip = img + ((size_t)(b * CIN + i)) * HH * WW;
#pragma unroll
    for (int ky = 0; ky < 3; ++ky) {
      int yy = y + ky - 1;
      if (yy < 0 || yy > 63) continue;
#pragma unroll
      for (int kx = 0; kx < 3; ++kx) {
        int xx = x + kx - 1;
        float iv = (xx >= 0 && xx < 64) ? ip[yy * 64 + xx] : 0.f;
        acc += wp[ky * 3 + kx] * m * iv;
      }
    }
  }
  out[((size_t)(b * CO + o) * HH + y) * WW + x] = acc * sig;
}

extern "C" void kernel_launch(void* const* d_in, const int* in_sizes, int n_in,
                              void* d_out, int out_size, void* d_ws, size_t ws_size,
                              hipStream_t stream) {
  const float* img    = (const float*)d_in[0];
  const float* s      = (const float*)d_in[1];
  const float* weight = (const float*)d_in[2];
  float* out = (float*)d_out;
  char* ws = (char*)d_ws;
  float* sigma = (float*)ws;

  if (ws_size >= WS_NEED) {
    u16* wmod = (u16*)(ws + SIG_BYTES);
    u16* imgt = (u16*)(ws + SIG_BYTES + WMOD_BYTES);
    k_sigma<<<512, 256, 0, stream>>>(weight, s, sigma);
    k_wmod<<<256, 256, 0, stream>>>(weight, s, sigma, wmod);
    k_pad<<<528, 256, 0, stream>>>(imgt);
    k_imgt<<<8192, 256, 0, stream>>>(img, imgt);
    k_conv<<<1024, 256, 0, stream>>>(wmod, imgt, out);
  } else {
    k_sigma<<<512, 256, 0, stream>>>(weight, s, sigma);
    k_naive<<<BB * CO * HH, 64, 0, stream>>>(img, s, weight, sigma, out);
  }
}